// Round 5
// baseline (2595.186 us; speedup 1.0000x reference)
//
#include <hip/hip_runtime.h>
#include <math.h>

#define Bb 1024
#define Ll 30
#define Dd 300
#define Hh 20
#define HDd 20

// One block per (b,h). 256 threads = 8 row-groups (ti) x 32 lanes (tj).
// Each thread: 4 rows (r0..r0+3) x 10 e-chunks (e = tj + 32k).
__global__ __launch_bounds__(256, 3)
void mha_fused_fp32(const float* __restrict__ y,
                    const int* __restrict__ seq,
                    const float* __restrict__ Q,
                    const float* __restrict__ V,
                    float* __restrict__ out)
{
    __shared__ float ys[32][320];     // y[b] rows, cols 300..319 zeroed, rows 30,31 zeroed
    __shared__ float alphaS[32][33];  // stride 33 -> bank-spread for l-varying reads
    __shared__ float Plds[32][20];    // P = y[b] @ V[h]  [30][20]
    __shared__ float maskS[32];

    const int bid = blockIdx.x;
    const int h = bid >> 10;        // grid = Hh * Bb, b fastest -> consecutive blocks share Q[h]
    const int b = bid & 1023;

    const int tid = threadIdx.x;
    const int tj = tid & 31;
    const int ti = tid >> 5;
    const int r0 = ti * 4;

    // ---- Stage A: y[b] -> LDS (zero pads), mask ----
    const float* yb = y + b * (Ll * Dd);
    for (int i = tid; i < 32 * 320; i += 256) {
        int row = i / 320;
        int col = i - row * 320;
        float v = 0.f;
        if (row < Ll && col < Dd) v = yb[row * Dd + col];
        ys[row][col] = v;
    }
    if (tid < 32) {
        float m = 0.f;
        if (tid < Ll) m = (seq[b * Ll + tid] > 0) ? 1.f : 0.f;
        maskS[tid] = m;
    }
    __syncthreads();

    // ---- Stage B: a1[l][e] = sum_d ys[l][d] * Q[h][d][e], kept in registers ----
    float a1reg[4][10];
    #pragma unroll
    for (int r = 0; r < 4; ++r)
        #pragma unroll
        for (int k = 0; k < 10; ++k) a1reg[r][k] = 0.f;

    const float* Qh = Q + h * (Dd * Dd) + tj;
    for (int d0 = 0; d0 < Dd; d0 += 4) {
        float ysv[4][4];
        #pragma unroll
        for (int r = 0; r < 4; ++r) {
            float4 t = *reinterpret_cast<const float4*>(&ys[r0 + r][d0]);
            ysv[r][0] = t.x; ysv[r][1] = t.y; ysv[r][2] = t.z; ysv[r][3] = t.w;
        }
        #pragma unroll
        for (int dd = 0; dd < 4; ++dd) {
            const float* qp = Qh + (d0 + dd) * Dd;
            float qv[10];
            #pragma unroll
            for (int k = 0; k < 9; ++k) qv[k] = qp[32 * k];
            qv[9] = (tj < 12) ? qp[288] : 0.f;   // e = tj+288 < 300 only for tj<12
            #pragma unroll
            for (int r = 0; r < 4; ++r) {
                float yd = ysv[r][dd];
                #pragma unroll
                for (int k = 0; k < 10; ++k)
                    a1reg[r][k] = fmaf(yd, qv[k], a1reg[r][k]);
            }
        }
    }

    // ---- Stage C: S[l][m] = sum_e a1[l][e] * ys[m][e]; butterfly over 32 lanes ----
    float Sreg[4] = {0.f, 0.f, 0.f, 0.f};  // ends up holding S[r0+r][m=tj]
    for (int m = 0; m < Ll; ++m) {
        float yv[10];
        #pragma unroll
        for (int k = 0; k < 10; ++k) yv[k] = ys[m][tj + 32 * k]; // pad cols are 0
        float part[4];
        #pragma unroll
        for (int r = 0; r < 4; ++r) {
            float s = 0.f;
            #pragma unroll
            for (int k = 0; k < 10; ++k) s = fmaf(a1reg[r][k], yv[k], s);
            part[r] = s;
        }
        #pragma unroll
        for (int off = 16; off >= 1; off >>= 1)
            #pragma unroll
            for (int r = 0; r < 4; ++r)
                part[r] += __shfl_xor(part[r], off, 64);
        #pragma unroll
        for (int r = 0; r < 4; ++r)
            if (tj == m) Sreg[r] = part[r];
    }

    // ---- softmax-like ratio (row-max shifted; exact algebra vs reference) ----
    const float maskv = maskS[tj];
    float Areg[4];
    #pragma unroll
    for (int r = 0; r < 4; ++r) {
        float v = (tj < Ll) ? Sreg[r] : -3.4e38f;
        #pragma unroll
        for (int off = 16; off >= 1; off >>= 1)
            v = fmaxf(v, __shfl_xor(v, off, 64));
        // v = M_l (row max over valid m)
        float e = __expf(Sreg[r] - v);
        float s = (tj < Ll) ? e * maskv : 0.f;
        #pragma unroll
        for (int off = 16; off >= 1; off >>= 1)
            s += __shfl_xor(s, off, 64);
        float denom = s + 1e-6f * __expf(-v);
        Areg[r] = e / denom;
    }
    #pragma unroll
    for (int r = 0; r < 4; ++r)
        if (r0 + r < Ll && tj < Ll) alphaS[r0 + r][tj] = Areg[r];

    // ---- Stage D: P[m][f] = sum_d ys[m][d] * V[h][d][f] ----
    float Pacc[4] = {0.f, 0.f, 0.f, 0.f};
    if (tj < HDd) {
        const float* Vh = V + h * (Dd * HDd) + tj;
        for (int d0 = 0; d0 < Dd; d0 += 4) {
            float ysv[4][4];
            #pragma unroll
            for (int r = 0; r < 4; ++r) {
                float4 t = *reinterpret_cast<const float4*>(&ys[r0 + r][d0]);
                ysv[r][0] = t.x; ysv[r][1] = t.y; ysv[r][2] = t.z; ysv[r][3] = t.w;
            }
            float vv[4];
            #pragma unroll
            for (int dd = 0; dd < 4; ++dd) vv[dd] = Vh[(d0 + dd) * HDd];
            #pragma unroll
            for (int r = 0; r < 4; ++r)
                #pragma unroll
                for (int dd = 0; dd < 4; ++dd)
                    Pacc[r] = fmaf(ysv[r][dd], vv[dd], Pacc[r]);
        }
    }
    #pragma unroll
    for (int r = 0; r < 4; ++r)
        if (tj < HDd && r0 + r < Ll) Plds[r0 + r][tj] = Pacc[r];
    __syncthreads();

    // ---- Stage E: out[b][l][h*HD+f] = sum_m alpha[l][m] * P[m][f] ----
    float* outb = out + b * (Ll * Hh * HDd) + h * HDd;
    for (int t = tid; t < Ll * HDd; t += 256) {
        int l = t / HDd;
        int f = t - l * HDd;
        float acc = 0.f;
        #pragma unroll
        for (int m = 0; m < Ll; ++m)
            acc = fmaf(alphaS[l][m], Plds[m][f], acc);
        outb[l * (Hh * HDd) + f] = acc;
    }
}

extern "C" void kernel_launch(void* const* d_in, const int* in_sizes, int n_in,
                              void* d_out, int out_size, void* d_ws, size_t ws_size,
                              hipStream_t stream) {
    (void)in_sizes; (void)n_in; (void)d_ws; (void)ws_size; (void)out_size;
    const float* y   = (const float*)d_in[0];
    const int*   seq = (const int*)d_in[1];
    const float* Q   = (const float*)d_in[2];
    const float* V   = (const float*)d_in[3];
    float* out = (float*)d_out;
    dim3 grid(Bb * Hh);
    dim3 block(256);
    hipLaunchKernelGGL(mha_fused_fp32, grid, block, 0, stream, y, seq, Q, V, out);
}

// Round 6
// 1254.252 us; speedup vs baseline: 2.0691x; 2.0691x over previous
//
#include <hip/hip_runtime.h>
#include <math.h>

#define Bb 1024
#define Ll 30
#define Dd 300
#define Hh 20
#define HDd 20

typedef __attribute__((ext_vector_type(8))) short short8;
typedef __attribute__((ext_vector_type(4))) float f32x4;

// ws packing: Q fragments [h][nt=19][ks=10][lane=64][8], hi then lo; V likewise [h][nt=2][ks=10][64][8]
#define QELEMS (Hh*19*10*64*8)   // 1,945,600 bf16 per half
#define VELEMS (Hh*2*10*64*8)    // 204,800
#define WS_NEEDED ((size_t)(2*QELEMS + 2*VELEMS) * 2)  // 8,601,600 bytes

__device__ __forceinline__ void bf16split(float x, unsigned short& h, unsigned short& l) {
    unsigned u = __float_as_uint(x);
    unsigned hr = (u + 0x7FFFu + ((u >> 16) & 1u)) >> 16;
    float hf = __uint_as_float(hr << 16);
    float r = x - hf;
    unsigned v = __float_as_uint(r);
    unsigned lr = (v + 0x7FFFu + ((v >> 16) & 1u)) >> 16;
    h = (unsigned short)hr; l = (unsigned short)lr;
}

// ---- prep: pack Q into B-fragment layout (bf16 hi/lo), zero-padded ----
__global__ void pack_q(const float* __restrict__ Q,
                       unsigned short* __restrict__ qh, unsigned short* __restrict__ ql) {
    int g = blockIdx.x * blockDim.x + threadIdx.x;
    if (g >= Hh*19*10*64) return;
    int l = g & 63;
    int t = g >> 6;
    int ks = t % 10; t /= 10;
    int nt = t % 19; int h = t / 19;
    int e = 16*nt + (l & 15);
    int kbase = 32*ks + 8*(l >> 4);
    unsigned hp[4], lp[4];
    #pragma unroll
    for (int p = 0; p < 4; ++p) {
        int k0 = kbase + 2*p, k1 = k0 + 1;
        float x0 = (k0 < Dd && e < Dd) ? Q[h*Dd*Dd + k0*Dd + e] : 0.f;
        float x1 = (k1 < Dd && e < Dd) ? Q[h*Dd*Dd + k1*Dd + e] : 0.f;
        unsigned short h0,l0,h1,l1;
        bf16split(x0,h0,l0); bf16split(x1,h1,l1);
        hp[p] = (unsigned)h0 | ((unsigned)h1 << 16);
        lp[p] = (unsigned)l0 | ((unsigned)l1 << 16);
    }
    ((uint4*)qh)[g] = make_uint4(hp[0],hp[1],hp[2],hp[3]);
    ((uint4*)ql)[g] = make_uint4(lp[0],lp[1],lp[2],lp[3]);
}

__global__ void pack_v(const float* __restrict__ V,
                       unsigned short* __restrict__ vh, unsigned short* __restrict__ vl) {
    int g = blockIdx.x * blockDim.x + threadIdx.x;
    if (g >= Hh*2*10*64) return;
    int l = g & 63;
    int t = g >> 6;
    int ks = t % 10; t /= 10;
    int nt = t % 2; int h = t / 2;
    int f = 16*nt + (l & 15);
    int kbase = 32*ks + 8*(l >> 4);
    unsigned hp[4], lp[4];
    #pragma unroll
    for (int p = 0; p < 4; ++p) {
        int k0 = kbase + 2*p, k1 = k0 + 1;
        float x0 = (k0 < Dd && f < HDd) ? V[h*Dd*HDd + k0*HDd + f] : 0.f;
        float x1 = (k1 < Dd && f < HDd) ? V[h*Dd*HDd + k1*HDd + f] : 0.f;
        unsigned short h0,l0,h1,l1;
        bf16split(x0,h0,l0); bf16split(x1,h1,l1);
        hp[p] = (unsigned)h0 | ((unsigned)h1 << 16);
        lp[p] = (unsigned)l0 | ((unsigned)l1 << 16);
    }
    ((uint4*)vh)[g] = make_uint4(hp[0],hp[1],hp[2],hp[3]);
    ((uint4*)vl)[g] = make_uint4(lp[0],lp[1],lp[2],lp[3]);
}

// ---- main: one block per (b,h), 512 threads = 8 waves ----
__global__ __launch_bounds__(512, 1)
void mha_mfma(const float* __restrict__ y, const int* __restrict__ seq,
              const unsigned short* __restrict__ qh, const unsigned short* __restrict__ ql,
              const unsigned short* __restrict__ vh, const unsigned short* __restrict__ vl,
              float* __restrict__ out)
{
    // y and a1 as bf16 hi/lo, [32 rows][320 cols], 16B-chunk XOR swizzle: chunk ^= (row&7)
    __shared__ __align__(16) unsigned short y_h[32*320], y_l[32*320];
    __shared__ __align__(16) unsigned short a_h[32*320], a_l[32*320];
    __shared__ float Smat[32][33];
    __shared__ float Pmat[32][21];
    __shared__ float maskS[32];

    const int bid = blockIdx.x;
    const int h = bid >> 10, b = bid & 1023;   // b fastest: blocks sharing h are adjacent (Q L2 reuse)
    const int tid = threadIdx.x;
    const int lane = tid & 63, wid = tid >> 6;
    const int lrow = lane & 15, lk = lane >> 4, l7 = lane & 7;

    // ---- phase 1: y -> swizzled bf16 hi/lo LDS; zero a1 pad chunks; mask ----
    const float* yb = y + b * (Ll * Dd);
    for (int idx = tid; idx < 32*320; idx += 512) {
        int row = idx / 320, e = idx - row*320;
        float v = (row < Ll && e < Dd) ? yb[row*Dd + e] : 0.f;
        unsigned short hv, lv; bf16split(v, hv, lv);
        int sidx = row*320 + (((e>>3) ^ (row&7))<<3) + (e&7);
        y_h[sidx] = hv; y_l[sidx] = lv;
    }
    if (tid < 128) {  // zero a1 chunks 38,39 (cols 304-319) so stage-C K-tail reads 0, not junk
        int arr = tid & 1, r = (tid>>1) & 31, c = (tid>>6) & 1;
        int sc = (38 + c) ^ (r & 7);
        unsigned short* p = arr ? a_l : a_h;
        *((uint4*)&p[r*320 + sc*8]) = make_uint4(0,0,0,0);
    }
    if (tid < 32)
        maskS[tid] = (tid < Ll && seq[b*Ll + tid] > 0) ? 1.f : 0.f;
    __syncthreads();

    // ---- phase 2: a1 = y·Q via MFMA, 3-product bf16 split; repack D-frags -> a1 LDS ----
    for (int nt = wid; nt < 19; nt += 8) {
        f32x4 acc0 = {0.f,0.f,0.f,0.f}, acc1 = {0.f,0.f,0.f,0.f};
        const unsigned short* qhp = qh + (size_t)(((h*19 + nt)*10)*64 + lane)*8;
        const unsigned short* qlp = ql + (size_t)(((h*19 + nt)*10)*64 + lane)*8;
        #pragma unroll 2
        for (int ks = 0; ks < 10; ++ks) {
            short8 bh = *(const short8*)(qhp + ks*512);
            short8 bl = *(const short8*)(qlp + ks*512);
            int sc = (lk + 4*ks) ^ l7;
            int i0 = lrow*320 + sc*8;
            int i1 = (lrow+16)*320 + sc*8;
            short8 rA0h = *(const short8*)&y_h[i0];
            short8 rA0l = *(const short8*)&y_l[i0];
            short8 rA1h = *(const short8*)&y_h[i1];
            short8 rA1l = *(const short8*)&y_l[i1];
            acc0 = __builtin_amdgcn_mfma_f32_16x16x32_bf16(rA0h, bh, acc0, 0,0,0);
            acc1 = __builtin_amdgcn_mfma_f32_16x16x32_bf16(rA1h, bh, acc1, 0,0,0);
            acc0 = __builtin_amdgcn_mfma_f32_16x16x32_bf16(rA0l, bh, acc0, 0,0,0);
            acc1 = __builtin_amdgcn_mfma_f32_16x16x32_bf16(rA1l, bh, acc1, 0,0,0);
            acc0 = __builtin_amdgcn_mfma_f32_16x16x32_bf16(rA0h, bl, acc0, 0,0,0);
            acc1 = __builtin_amdgcn_mfma_f32_16x16x32_bf16(rA1h, bl, acc1, 0,0,0);
        }
        int e = 16*nt + lrow;
        int ecl = e >> 3, ebit = e & 7;
        #pragma unroll
        for (int Mt = 0; Mt < 2; ++Mt) {
            f32x4 a = Mt ? acc1 : acc0;
            #pragma unroll
            for (int r = 0; r < 4; ++r) {
                int row = 16*Mt + 4*lk + r;
                unsigned short hv, lv; bf16split(a[r], hv, lv);
                int sidx = row*320 + ((ecl ^ (row&7))<<3) + ebit;
                a_h[sidx] = hv; a_l[sidx] = lv;
            }
        }
    }
    __syncthreads();

    // ---- phase 3: waves 0-3: S = a1·y^T; waves 4-7: P = y·V ----
    if (wid < 4) {
        int Mt = wid >> 1, Nt = wid & 1;
        f32x4 acc = {0.f,0.f,0.f,0.f};
        for (int ks = 0; ks < 10; ++ks) {
            int sc = (lk + 4*ks) ^ l7;
            int ia = (lrow + 16*Mt)*320 + sc*8;
            int ib = (lrow + 16*Nt)*320 + sc*8;
            short8 ah = *(const short8*)&a_h[ia];
            short8 al = *(const short8*)&a_l[ia];
            short8 bh = *(const short8*)&y_h[ib];
            short8 bl = *(const short8*)&y_l[ib];
            acc = __builtin_amdgcn_mfma_f32_16x16x32_bf16(ah, bh, acc, 0,0,0);
            acc = __builtin_amdgcn_mfma_f32_16x16x32_bf16(al, bh, acc, 0,0,0);
            acc = __builtin_amdgcn_mfma_f32_16x16x32_bf16(ah, bl, acc, 0,0,0);
        }
        #pragma unroll
        for (int r = 0; r < 4; ++r)
            Smat[16*Mt + 4*lk + r][16*Nt + lrow] = acc[r];
    } else {
        int w = wid - 4;
        int Mt = w >> 1, Nt = w & 1;
        f32x4 acc = {0.f,0.f,0.f,0.f};
        const unsigned short* vhp = vh + (size_t)(((h*2 + Nt)*10)*64 + lane)*8;
        const unsigned short* vlp = vl + (size_t)(((h*2 + Nt)*10)*64 + lane)*8;
        for (int ks = 0; ks < 10; ++ks) {
            short8 bh = *(const short8*)(vhp + ks*512);
            short8 bl = *(const short8*)(vlp + ks*512);
            int sc = (lk + 4*ks) ^ l7;
            int ia = (lrow + 16*Mt)*320 + sc*8;
            short8 ah = *(const short8*)&y_h[ia];
            short8 al = *(const short8*)&y_l[ia];
            acc = __builtin_amdgcn_mfma_f32_16x16x32_bf16(ah, bh, acc, 0,0,0);
            acc = __builtin_amdgcn_mfma_f32_16x16x32_bf16(al, bh, acc, 0,0,0);
            acc = __builtin_amdgcn_mfma_f32_16x16x32_bf16(ah, bl, acc, 0,0,0);
        }
        int f = 16*Nt + lrow;
        if (f < HDd) {
            #pragma unroll
            for (int r = 0; r < 4; ++r)
                Pmat[16*Mt + 4*lk + r][f] = acc[r];
        }
    }
    __syncthreads();

    // ---- phase 4: softmax-ratio (max-shifted, algebraically exact vs reference) ----
    {
        const int tj = tid & 31, ti = tid >> 5;   // 16 row-groups x 2 rows
        const float maskv = maskS[tj];
        #pragma unroll
        for (int r = 0; r < 2; ++r) {
            int row = ti*2 + r;
            float S = Smat[row][tj];
            float v = (tj < Ll) ? S : -3.4e38f;
            #pragma unroll
            for (int off = 16; off >= 1; off >>= 1)
                v = fmaxf(v, __shfl_xor(v, off, 64));
            float e = __expf(S - v);
            float s = (tj < Ll) ? e * maskv : 0.f;
            #pragma unroll
            for (int off = 16; off >= 1; off >>= 1)
                s += __shfl_xor(s, off, 64);
            float denom = s + 1e-6f * __expf(-v);
            float alph = e / denom;
            if (row < Ll && tj < Ll) Smat[row][tj] = alph;
        }
    }
    __syncthreads();

    // ---- phase 5: out = alpha · P ----
    for (int t = tid; t < Ll*HDd; t += 512) {
        int l = t / HDd, f = t - l*HDd;
        float acc = 0.f;
        #pragma unroll
        for (int m = 0; m < Ll; ++m)
            acc = fmaf(Smat[l][m], Pmat[m][f], acc);
        out[b*(Ll*Hh*HDd) + l*(Hh*HDd) + h*HDd + f] = acc;
    }
}

// ---- fallback (round-5 verified fp32 kernel), used if ws too small ----
__global__ __launch_bounds__(256, 3)
void mha_fused_fp32(const float* __restrict__ y,
                    const int* __restrict__ seq,
                    const float* __restrict__ Q,
                    const float* __restrict__ V,
                    float* __restrict__ out)
{
    __shared__ float ys[32][320];
    __shared__ float alphaS[32][33];
    __shared__ float Plds[32][20];
    __shared__ float maskS[32];

    const int bid = blockIdx.x;
    const int h = bid >> 10;
    const int b = bid & 1023;
    const int tid = threadIdx.x;
    const int tj = tid & 31;
    const int ti = tid >> 5;
    const int r0 = ti * 4;

    const float* yb = y + b * (Ll * Dd);
    for (int i = tid; i < 32 * 320; i += 256) {
        int row = i / 320;
        int col = i - row * 320;
        float v = 0.f;
        if (row < Ll && col < Dd) v = yb[row * Dd + col];
        ys[row][col] = v;
    }
    if (tid < 32) {
        float m = 0.f;
        if (tid < Ll) m = (seq[b * Ll + tid] > 0) ? 1.f : 0.f;
        maskS[tid] = m;
    }
    __syncthreads();

    float a1reg[4][10];
    #pragma unroll
    for (int r = 0; r < 4; ++r)
        #pragma unroll
        for (int k = 0; k < 10; ++k) a1reg[r][k] = 0.f;

    const float* Qh = Q + h * (Dd * Dd) + tj;
    for (int d0 = 0; d0 < Dd; d0 += 4) {
        float ysv[4][4];
        #pragma unroll
        for (int r = 0; r < 4; ++r) {
            float4 t = *reinterpret_cast<const float4*>(&ys[r0 + r][d0]);
            ysv[r][0] = t.x; ysv[r][1] = t.y; ysv[r][2] = t.z; ysv[r][3] = t.w;
        }
        #pragma unroll
        for (int dd = 0; dd < 4; ++dd) {
            const float* qp = Qh + (d0 + dd) * Dd;
            float qv[10];
            #pragma unroll
            for (int k = 0; k < 9; ++k) qv[k] = qp[32 * k];
            qv[9] = (tj < 12) ? qp[288] : 0.f;
            #pragma unroll
            for (int r = 0; r < 4; ++r) {
                float yd = ysv[r][dd];
                #pragma unroll
                for (int k = 0; k < 10; ++k)
                    a1reg[r][k] = fmaf(yd, qv[k], a1reg[r][k]);
            }
        }
    }

    float Sreg[4] = {0.f, 0.f, 0.f, 0.f};
    for (int m = 0; m < Ll; ++m) {
        float yv[10];
        #pragma unroll
        for (int k = 0; k < 10; ++k) yv[k] = ys[m][tj + 32 * k];
        float part[4];
        #pragma unroll
        for (int r = 0; r < 4; ++r) {
            float s = 0.f;
            #pragma unroll
            for (int k = 0; k < 10; ++k) s = fmaf(a1reg[r][k], yv[k], s);
            part[r] = s;
        }
        #pragma unroll
        for (int off = 16; off >= 1; off >>= 1)
            #pragma unroll
            for (int r = 0; r < 4; ++r)
                part[r] += __shfl_xor(part[r], off, 64);
        #pragma unroll
        for (int r = 0; r < 4; ++r)
            if (tj == m) Sreg[r] = part[r];
    }

    const float maskv = maskS[tj];
    float Areg[4];
    #pragma unroll
    for (int r = 0; r < 4; ++r) {
        float v = (tj < Ll) ? Sreg[r] : -3.4e38f;
        #pragma unroll
        for (int off = 16; off >= 1; off >>= 1)
            v = fmaxf(v, __shfl_xor(v, off, 64));
        float e = __expf(Sreg[r] - v);
        float s = (tj < Ll) ? e * maskv : 0.f;
        #pragma unroll
        for (int off = 16; off >= 1; off >>= 1)
            s += __shfl_xor(s, off, 64);
        float denom = s + 1e-6f * __expf(-v);
        Areg[r] = e / denom;
    }
    #pragma unroll
    for (int r = 0; r < 4; ++r)
        if (r0 + r < Ll && tj < Ll) alphaS[r0 + r][tj] = Areg[r];

    float Pacc[4] = {0.f, 0.f, 0.f, 0.f};
    if (tj < HDd) {
        const float* Vh = V + h * (Dd * HDd) + tj;
        for (int d0 = 0; d0 < Dd; d0 += 4) {
            float ysv[4][4];
            #pragma unroll
            for (int r = 0; r < 4; ++r) {
                float4 t = *reinterpret_cast<const float4*>(&ys[r0 + r][d0]);
                ysv[r][0] = t.x; ysv[r][1] = t.y; ysv[r][2] = t.z; ysv[r][3] = t.w;
            }
            float vv[4];
            #pragma unroll
            for (int dd = 0; dd < 4; ++dd) vv[dd] = Vh[(d0 + dd) * HDd];
            #pragma unroll
            for (int r = 0; r < 4; ++r)
                #pragma unroll
                for (int dd = 0; dd < 4; ++dd)
                    Pacc[r] = fmaf(ysv[r][dd], vv[dd], Pacc[r]);
        }
    }
    #pragma unroll
    for (int r = 0; r < 4; ++r)
        if (tj < HDd && r0 + r < Ll) Plds[r0 + r][tj] = Pacc[r];
    __syncthreads();

    float* outb = out + b * (Ll * Hh * HDd) + h * HDd;
    for (int t = tid; t < Ll * HDd; t += 256) {
        int l = t / HDd;
        int f = t - l * HDd;
        float acc = 0.f;
        #pragma unroll
        for (int m = 0; m < Ll; ++m)
            acc = fmaf(alphaS[l][m], Plds[m][f], acc);
        outb[l * (Hh * HDd) + f] = acc;
    }
}

extern "C" void kernel_launch(void* const* d_in, const int* in_sizes, int n_in,
                              void* d_out, int out_size, void* d_ws, size_t ws_size,
                              hipStream_t stream) {
    (void)in_sizes; (void)n_in; (void)out_size;
    const float* y   = (const float*)d_in[0];
    const int*   seq = (const int*)d_in[1];
    const float* Q   = (const float*)d_in[2];
    const float* V   = (const float*)d_in[3];
    float* out = (float*)d_out;

    if (ws_size < WS_NEEDED) {
        // fallback: verified round-5 fp32 kernel
        hipLaunchKernelGGL(mha_fused_fp32, dim3(Bb * Hh), dim3(256), 0, stream, y, seq, Q, V, out);
        return;
    }

    unsigned short* qh = (unsigned short*)d_ws;
    unsigned short* ql = qh + QELEMS;
    unsigned short* vh = ql + QELEMS;
    unsigned short* vl = vh + VELEMS;

    pack_q<<<dim3((Hh*19*10*64 + 255)/256), dim3(256), 0, stream>>>(Q, qh, ql);
    pack_v<<<dim3((Hh*2*10*64 + 255)/256), dim3(256), 0, stream>>>(V, vh, vl);
    mha_mfma<<<dim3(Bb * Hh), dim3(512), 0, stream>>>(y, seq, qh, ql, vh, vl, out);
}